// Round 1
// baseline (1195.938 us; speedup 1.0000x reference)
//
#include <hip/hip_runtime.h>
#include <hip/hip_bf16.h>

#define NTOT  16384
#define NN    70
#define EE    3
#define SS    10
#define STEPS 5
#define NB    8
#define NPAIR (NB*NN)   // 560
#define TPB   576       // 9 waves
#define PSTR  12        // prop row stride (floats): 48B -> float4-aligned rows
#define ASTR  71        // A row stride (bf16 elems): odd -> conflict-free-ish

// weight offsets (floats) inside sm.w
#define OFF_WIN 0
#define OFF_BIN 300
#define OFF_WR  330
#define OFF_BR  530
#define OFF_WZ  540
#define OFF_BZ  740
#define OFF_WH  750
#define OFF_BH  950
#define OFF_WO1 960
#define OFF_BO1 1070
#define OFF_WO2 1080
#define OFF_BO2 1090
#define NWTOT   1091

__device__ __forceinline__ float fast_sigmoid(float x) {
    return __builtin_amdgcn_rcpf(1.0f + __expf(-x));
}
__device__ __forceinline__ float fast_tanh(float x) {
    float ax = fabsf(x);
    float e  = __expf(-2.0f * ax);
    float t  = (1.0f - e) * __builtin_amdgcn_rcpf(1.0f + e);
    return copysignf(t, x);
}

struct __align__(16) Smem {
    float prop[NB*NN*PSTR];          // 26880 B, fp32 state
    __hip_bfloat16 A[EE*NN*ASTR];    // 29820 B, A transposed: A[em][n]
    float w[NWTOT + 1];              // 4368 B, all weights as fp32
    int flag;
};
// total ~61.1 KB static LDS

template<typename T>
__device__ __forceinline__ void run_impl(
    const void* annv, const void* Av, const void* winv, const void* binv,
    const void* wrv, const void* brv, const void* wzv, const void* bzv,
    const void* whv, const void* bhv, const void* wo1v, const void* bo1v,
    const void* wo2v, const void* bo2v, void* outv, Smem& sm)
{
    const T* ann_g = (const T*)annv;
    const T* A_g   = (const T*)Av;
    T* out_g       = (T*)outv;
    const int tid = threadIdx.x;
    const int blk = blockIdx.x;

    // ---- stage A transposed into LDS: global A[n*210+em] -> sm.A[em*ASTR+n]
    for (int idx = tid; idx < NN*NN*EE; idx += TPB) {
        const int n2 = idx / (NN*EE);
        const int em = idx - n2*(NN*EE);
        sm.A[em*ASTR + n2] = __float2bfloat16((float)A_g[idx]);
    }
    // ---- stage weights (convert to fp32)
    {
        const T* srcs[12] = {(const T*)winv,(const T*)binv,(const T*)wrv,(const T*)brv,
                             (const T*)wzv,(const T*)bzv,(const T*)whv,(const T*)bhv,
                             (const T*)wo1v,(const T*)bo1v,(const T*)wo2v,(const T*)bo2v};
        const int offs[12] = {OFF_WIN,OFF_BIN,OFF_WR,OFF_BR,OFF_WZ,OFF_BZ,
                              OFF_WH,OFF_BH,OFF_WO1,OFF_BO1,OFF_WO2,OFF_BO2};
        const int cnts[12] = {300,30,200,10,200,10,200,10,110,10,10,1};
        #pragma unroll 1
        for (int a = 0; a < 12; ++a)
            for (int k = tid; k < cnts[a]; k += TPB)
                sm.w[offs[a] + k] = (float)srcs[a][k];
    }

    const int p     = tid;
    const bool act  = (p < NPAIR);
    const int i_loc = p / NN;
    const int n     = p - i_loc*NN;
    const int b     = blk*NB + i_loc;
    float* myrow = &sm.prop[(i_loc*NN + n)*PSTR];

    float ann = 0.f;
    float pr[SS];
    #pragma unroll
    for (int s = 0; s < SS; ++s) pr[s] = 0.f;
    if (act) {
        ann  = (float)ann_g[b*NN + n];
        pr[0] = ann;
        *(float4*)(myrow+0) = make_float4(ann,0.f,0.f,0.f);
        *(float4*)(myrow+4) = make_float4(0.f,0.f,0.f,0.f);
        *(float2*)(myrow+8) = make_float2(0.f,0.f);
    }
    __syncthreads();

    // ---- A row-sums per edge type (for bias through aggregation), once
    float rs0 = 0.f, rs1 = 0.f, rs2 = 0.f;
    if (act) {
        const __hip_bfloat16* a0 = &sm.A[0*NN*ASTR + n];
        const __hip_bfloat16* a1 = &sm.A[1*NN*ASTR + n];
        const __hip_bfloat16* a2 = &sm.A[2*NN*ASTR + n];
        #pragma unroll 1
        for (int m = 0; m < NN; ++m) {
            rs0 += (float)a0[m*ASTR];
            rs1 += (float)a1[m*ASTR];
            rs2 += (float)a2[m*ASTR];
        }
    }

    #pragma unroll 1
    for (int step = 0; step < STEPS; ++step) {
        float a_in[SS];
        if (act) {
            float P[EE][SS];
            #pragma unroll
            for (int e = 0; e < EE; ++e)
                #pragma unroll
                for (int s = 0; s < SS; ++s) P[e][s] = 0.f;
            const float* prow = &sm.prop[i_loc*NN*PSTR];
            const __hip_bfloat16* a0 = &sm.A[0*NN*ASTR + n];
            const __hip_bfloat16* a1 = &sm.A[1*NN*ASTR + n];
            const __hip_bfloat16* a2 = &sm.A[2*NN*ASTR + n];
            #pragma unroll
            for (int m = 0; m < NN; ++m) {
                const float4 q0 = *(const float4*)(prow + m*PSTR);
                const float4 q1 = *(const float4*)(prow + m*PSTR + 4);
                const float2 q2 = *(const float2*)(prow + m*PSTR + 8);
                const float av0 = (float)a0[m*ASTR];
                const float av1 = (float)a1[m*ASTR];
                const float av2 = (float)a2[m*ASTR];
                const float q[SS] = {q0.x,q0.y,q0.z,q0.w,q1.x,q1.y,q1.z,q1.w,q2.x,q2.y};
                #pragma unroll
                for (int s = 0; s < SS; ++s) {
                    P[0][s] += av0*q[s];
                    P[1][s] += av1*q[s];
                    P[2][s] += av2*q[s];
                }
            }
            // per-edge output transform + aggregated bias
            #pragma unroll
            for (int s = 0; s < SS; ++s) {
                float acc = rs0*sm.w[OFF_BIN+s] + rs1*sm.w[OFF_BIN+SS+s] + rs2*sm.w[OFF_BIN+2*SS+s];
                #pragma unroll
                for (int e = 0; e < EE; ++e)
                    #pragma unroll
                    for (int t = 0; t < SS; ++t)
                        acc += sm.w[OFF_WIN + e*SS*SS + s*SS + t] * P[e][t];
                a_in[s] = acc;
            }
        }
        __syncthreads();   // all prop reads done before anyone overwrites
        if (act) {
            float rv[SS], hh[SS], zv[SS];
            #pragma unroll
            for (int s = 0; s < SS; ++s) {
                float acc = sm.w[OFF_BR+s];
                #pragma unroll
                for (int d = 0; d < SS; ++d) acc += a_in[d]*sm.w[OFF_WR + s*2*SS + d];
                #pragma unroll
                for (int d = 0; d < SS; ++d) acc += pr[d]*sm.w[OFF_WR + s*2*SS + SS + d];
                rv[s] = fast_sigmoid(acc);
            }
            #pragma unroll
            for (int s = 0; s < SS; ++s) rv[s] *= pr[s];   // r * prop
            #pragma unroll
            for (int s = 0; s < SS; ++s) {
                float acc = sm.w[OFF_BH+s];
                #pragma unroll
                for (int d = 0; d < SS; ++d) acc += a_in[d]*sm.w[OFF_WH + s*2*SS + d];
                #pragma unroll
                for (int d = 0; d < SS; ++d) acc += rv[d]*sm.w[OFF_WH + s*2*SS + SS + d];
                hh[s] = fast_tanh(acc);
            }
            #pragma unroll
            for (int s = 0; s < SS; ++s) {
                float acc = sm.w[OFF_BZ+s];
                #pragma unroll
                for (int d = 0; d < SS; ++d) acc += a_in[d]*sm.w[OFF_WZ + s*2*SS + d];
                #pragma unroll
                for (int d = 0; d < SS; ++d) acc += pr[d]*sm.w[OFF_WZ + s*2*SS + SS + d];
                zv[s] = fast_sigmoid(acc);
            }
            #pragma unroll
            for (int s = 0; s < SS; ++s) pr[s] += zv[s]*(hh[s]-pr[s]);
            *(float4*)(myrow+0) = make_float4(pr[0],pr[1],pr[2],pr[3]);
            *(float4*)(myrow+4) = make_float4(pr[4],pr[5],pr[6],pr[7]);
            *(float2*)(myrow+8) = make_float2(pr[8],pr[9]);
        }
        __syncthreads();   // new prop visible for next step
    }

    // ---- epilogue: out = tanh([prop, ann] @ Wo1^T + bo1) @ Wo2^T + bo2
    if (act) {
        float o = sm.w[OFF_BO2];
        #pragma unroll
        for (int s = 0; s < SS; ++s) {
            float acc = sm.w[OFF_BO1+s] + ann*sm.w[OFF_WO1 + s*(SS+1) + SS];
            #pragma unroll
            for (int d = 0; d < SS; ++d) acc += pr[d]*sm.w[OFF_WO1 + s*(SS+1) + d];
            o += fast_tanh(acc) * sm.w[OFF_WO2 + s];
        }
        out_g[b*NN + n] = (T)o;
    }
}

__global__ __launch_bounds__(TPB, 5)
void ggnn_kernel(const void* annv, const void* Av, const void* winv, const void* binv,
                 const void* wrv, const void* brv, const void* wzv, const void* bzv,
                 const void* whv, const void* bhv, const void* wo1v, const void* bo1v,
                 const void* wo2v, const void* bo2v, void* outv)
{
    __shared__ Smem sm;
    // ---- runtime dtype probe on annotation: bf16 elems have plausible exponents,
    // fp32 low mantissa halves (every other u16) mostly don't. Deterministic.
    if (threadIdx.x == 0) {
        const unsigned short* u = (const unsigned short*)annv;
        int good = 0;
        for (int k = 0; k < 128; ++k) {
            unsigned short bb = u[k];
            int ex = (bb >> 7) & 0xFF;
            if (bb == 0 || (ex >= 101 && ex <= 131)) ++good;
        }
        sm.flag = (good >= 112) ? 1 : 0;
    }
    __syncthreads();
    if (sm.flag)
        run_impl<__hip_bfloat16>(annv,Av,winv,binv,wrv,brv,wzv,bzv,whv,bhv,wo1v,bo1v,wo2v,bo2v,outv,sm);
    else
        run_impl<float>(annv,Av,winv,binv,wrv,brv,wzv,bzv,whv,bhv,wo1v,bo1v,wo2v,bo2v,outv,sm);
}

extern "C" void kernel_launch(void* const* d_in, const int* in_sizes, int n_in,
                              void* d_out, int out_size, void* d_ws, size_t ws_size,
                              hipStream_t stream) {
    (void)in_sizes; (void)n_in; (void)out_size; (void)d_ws; (void)ws_size;
    dim3 grid(NTOT / NB);   // 2048 blocks, each owns 8 batch elements
    dim3 block(TPB);
    hipLaunchKernelGGL(ggnn_kernel, grid, block, 0, stream,
        d_in[0], d_in[1], d_in[2], d_in[3], d_in[4], d_in[5], d_in[6],
        d_in[7], d_in[8], d_in[9], d_in[10], d_in[11], d_in[12], d_in[13],
        d_out);
}